// Round 9
// baseline (824.469 us; speedup 1.0000x reference)
//
#include <hip/hip_runtime.h>
#include <hip/hip_bf16.h>
#include <cmath>

using bf16 = __hip_bfloat16;
typedef __bf16 v8bf __attribute__((ext_vector_type(8)));
typedef __bf16 v4bf __attribute__((ext_vector_type(4)));
typedef float  v4f  __attribute__((ext_vector_type(4)));

__device__ __forceinline__ float bf2f(bf16 x) { return __bfloat162float(x); }
__device__ __forceinline__ bf16  f2bf(float x) { return __float2bfloat16(x); }
__device__ __forceinline__ __bf16 tobf(float x) {
    bf16 h = __float2bfloat16(x);
    return __builtin_bit_cast(__bf16, h);
}

// async global->LDS, 16B per lane (lds dest = wave-uniform base + lane*16)
__device__ __forceinline__ void gll16(const bf16* g, bf16* l) {
    __builtin_amdgcn_global_load_lds(
        (const __attribute__((address_space(1))) unsigned int*)g,
        (__attribute__((address_space(3))) unsigned int*)l, 16, 0, 0);
}

// T1 XCD-aware swizzle: hardware round-robins the linear dispatch slot across
// 8 XCD L2s; remap so each XCD gets a CONTIGUOUS run of logical tiles
// (consecutive tiles share B-panels + contiguous A rows -> L2 hits).
// Requires gridDim.x*gridDim.y % 8 == 0 (all our GEMM grids: 640/512/256).
__device__ __forceinline__ int2 xcd_swz() {
    int nx = (int)gridDim.x;
    int nwg = nx * (int)gridDim.y;
    int slot = (int)blockIdx.y * nx + (int)blockIdx.x;
    int cpx = nwg >> 3;
    int lg = (slot & 7) * cpx + (slot >> 3);
    return make_int2(lg % nx, lg / nx);
}

__device__ __forceinline__ float ldin(const void* p, size_t i, int isf32) {
    if (isf32) return ((const float*)p)[i];
    return bf2f(((const bf16*)p)[i]);
}

// flag-dtype vector load of 8 consecutive elements
__device__ __forceinline__ void ld8(const void* p, size_t base, int f, float v[8]) {
    if (f) {
        const float* pf = (const float*)p + base;
        float4 a = *(const float4*)pf, b = *(const float4*)(pf + 4);
        v[0]=a.x; v[1]=a.y; v[2]=a.z; v[3]=a.w;
        v[4]=b.x; v[5]=b.y; v[6]=b.z; v[7]=b.w;
    } else {
        v8bf a = *(const v8bf*)((const bf16*)p + base);
#pragma unroll
        for (int j = 0; j < 8; ++j) v[j] = (float)a[j];
    }
}

__device__ __forceinline__ float wave_sum(float v) {
#pragma unroll
    for (int o = 32; o > 0; o >>= 1) v += __shfl_xor(v, o, 64);
    return v;
}
__device__ __forceinline__ float wave_max(float v) {
#pragma unroll
    for (int o = 32; o > 0; o >>= 1) v = fmaxf(v, __shfl_xor(v, o, 64));
    return v;
}

// ---------------- dtype detector -------------------------------------------
__global__ void detect_k(const unsigned short* __restrict__ x, int* __restrict__ flag)
{
    __shared__ int s;
    int t = threadIdx.x;
    if (t == 0) s = 0;
    __syncthreads();
    int bad = 0;
    for (int i = t; i < 4096; i += 256) {
        int e = (x[i] >> 7) & 0xFF;
        if (e >= 147) bad++;
    }
    atomicAdd(&s, bad);
    __syncthreads();
    if (t == 0) *flag = (s > 64) ? 1 : 0;
}

// ============ 256x256 / BK=64 / 8-wave double-buffered GEMM + SiLU ===========
// 2-phase pipeline: stage K-tile t+1 into buf^1 (async global_load_lds) BEFORE
// computing K-tile t from buf; the single __syncthreads() per tile drains
// vmcnt (stage complete) + lgkmcnt (reads complete).
// Swizzle (both-sides, rule #21): 16B-granule g within a 128B row is stored at
// linear LDS slot but sourced from global granule g^(row&7); ds_read applies
// the same XOR.
// BT is the PERMUTED W1^T (a/gate interleave, groups of 64 rows = 32 a + 32
// gate): each wave's 64-col span is exactly one group; acc[mt][nt] (nt<2)
// pairs with acc[mt][nt+2] as (a, gate). U is 4096x2048.
__global__ __launch_bounds__(512, 2)
void gemm256_silu(const bf16* __restrict__ A, const bf16* __restrict__ BT,
                  bf16* __restrict__ U, int K, int lda)
{
    __shared__ bf16 As[2][256 * 64];
    __shared__ bf16 Bs[2][256 * 64];
    const int t = threadIdx.x;            // 0..511
    const int lane = t & 63;
    const int wave = t >> 6;              // 0..7  (2 M x 4 N)
    const int wm = (wave >> 2) * 128;
    const int wn = (wave & 3) * 64;
    const int2 bxy = xcd_swz();
    const int bm = bxy.x * 256;
    const int bn = bxy.y * 256;
    const int fr = lane & 15;
    const int quad = lane >> 4;

    v4f acc[8][4];
#pragma unroll
    for (int i = 0; i < 8; ++i)
#pragma unroll
        for (int j = 0; j < 4; ++j) { v4f z = {0.f, 0.f, 0.f, 0.f}; acc[i][j] = z; }

    auto stage = [&](int buf, int k0) {
#pragma unroll
        for (int r = 0; r < 4; ++r) {
            int c = t + 512 * r;
            int row = c >> 3;
            int g = (c & 7) ^ (row & 7);
            gll16(A + (size_t)(bm + row) * lda + k0 + g * 8, &As[buf][c * 8]);
            gll16(BT + (size_t)(bn + row) * K + k0 + g * 8, &Bs[buf][c * 8]);
        }
    };

    stage(0, 0);
    __syncthreads();
    const int nb = K >> 6;                 // K/64 tiles
    for (int kt = 0; kt < nb; ++kt) {
        const int buf = kt & 1;
        if (kt + 1 < nb) stage(buf ^ 1, (kt + 1) * 64);
#pragma unroll
        for (int ks = 0; ks < 2; ++ks) {
            v8bf af[8], bfr[4];
            const int gk = ((ks * 4 + quad) ^ (fr & 7)) * 8;
#pragma unroll
            for (int mt = 0; mt < 8; ++mt)
                af[mt] = *(const v8bf*)(&As[buf][(wm + mt * 16 + fr) * 64 + gk]);
#pragma unroll
            for (int nt = 0; nt < 4; ++nt)
                bfr[nt] = *(const v8bf*)(&Bs[buf][(wn + nt * 16 + fr) * 64 + gk]);
#pragma unroll
            for (int mt = 0; mt < 8; ++mt)
#pragma unroll
                for (int nt = 0; nt < 4; ++nt)
                    acc[mt][nt] = __builtin_amdgcn_mfma_f32_16x16x32_bf16(
                        af[mt], bfr[nt], acc[mt][nt], 0, 0, 0);
        }
        __syncthreads();                   // drains stage (vmcnt) + reads done
    }

    const int r0 = quad * 4;
    const int gbase = ((bn + wn) >> 6) * 32;
#pragma unroll
    for (int mt = 0; mt < 8; ++mt)
#pragma unroll
        for (int nt = 0; nt < 2; ++nt)
#pragma unroll
            for (int r = 0; r < 4; ++r) {
                int row = bm + wm + mt * 16 + r0 + r;
                int col = gbase + nt * 16 + fr;
                float a  = acc[mt][nt][r];
                float gg = acc[mt][nt + 2][r];
                U[(size_t)row * 2048 + col] = f2bf(a * (gg / (1.f + __expf(-gg))));
            }
}

// ========= MFMA GEMM 64x64 / BK=64 double-buffered (async LDS staging) =======
// Tile 64x64 so the grid doubles (512-640 blocks = 2-2.5 blocks/CU):
// cross-block wave overlap (m114) hides the per-tile barrier drain.
// Swizzle identical to gemm256_silu (granule g ^ (row&7), both sides).
__global__ __launch_bounds__(256)
void gemm64(const bf16* __restrict__ A, const bf16* __restrict__ BT,
            bf16* __restrict__ C, int M, int N, int K, int lda)
{
    __shared__ bf16 As[2][64 * 64];
    __shared__ bf16 Bs[2][64 * 64];
    const int t = threadIdx.x;
    const int lane = t & 63;
    const int wave = t >> 6;
    const int wm = (wave >> 1) * 32;
    const int wn = (wave & 1) * 32;
    const int2 bxy = xcd_swz();
    const int bm = bxy.x * 64;
    const int bn = bxy.y * 64;
    const int fr = lane & 15;
    const int quad = lane >> 4;

    v4f acc[2][2];
#pragma unroll
    for (int i = 0; i < 2; ++i)
#pragma unroll
        for (int j = 0; j < 2; ++j) { v4f z = {0.f, 0.f, 0.f, 0.f}; acc[i][j] = z; }

    auto stage = [&](int buf, int k0) {
#pragma unroll
        for (int r = 0; r < 2; ++r) {            // A,B: 64x64 = 512 granules each
            int c = t + 256 * r;
            int row = c >> 3;
            int g = (c & 7) ^ (row & 7);
            gll16(A + (size_t)(bm + row) * lda + k0 + g * 8, &As[buf][c * 8]);
            gll16(BT + (size_t)(bn + row) * K + k0 + g * 8, &Bs[buf][c * 8]);
        }
    };

    stage(0, 0);
    __syncthreads();
    const int nb = K >> 6;
    for (int kt = 0; kt < nb; ++kt) {
        const int buf = kt & 1;
        if (kt + 1 < nb) stage(buf ^ 1, (kt + 1) * 64);
#pragma unroll
        for (int ks = 0; ks < 2; ++ks) {
            v8bf af[2], bfr[2];
            const int gk = ((ks * 4 + quad) ^ (fr & 7)) * 8;
#pragma unroll
            for (int mt = 0; mt < 2; ++mt)
                af[mt] = *(const v8bf*)(&As[buf][(wm + mt * 16 + fr) * 64 + gk]);
#pragma unroll
            for (int nt = 0; nt < 2; ++nt)
                bfr[nt] = *(const v8bf*)(&Bs[buf][(wn + nt * 16 + fr) * 64 + gk]);
#pragma unroll
            for (int mt = 0; mt < 2; ++mt)
#pragma unroll
                for (int nt = 0; nt < 2; ++nt)
                    acc[mt][nt] = __builtin_amdgcn_mfma_f32_16x16x32_bf16(
                        af[mt], bfr[nt], acc[mt][nt], 0, 0, 0);
        }
        __syncthreads();
    }
    const int r0 = quad * 4;
#pragma unroll
    for (int mt = 0; mt < 2; ++mt)
#pragma unroll
        for (int nt = 0; nt < 2; ++nt)
#pragma unroll
            for (int r = 0; r < 4; ++r) {
                int row = bm + wm + mt * 16 + r0 + r;
                int col = bn + wn + nt * 16 + fr;
                C[(size_t)row * N + col] = f2bf(acc[mt][nt][r]);
            }
}

// ---- gemm64 (64x64, BK=64 dbuf) with flag-selected output dtype -------------
__global__ __launch_bounds__(256)
void gemm64_out(const bf16* __restrict__ A, const bf16* __restrict__ BT,
                void* __restrict__ C, int M, int N, int K, int lda,
                const int* __restrict__ flag)
{
    __shared__ bf16 As[2][64 * 64];
    __shared__ bf16 Bs[2][64 * 64];
    const int f = *flag;
    const int t = threadIdx.x;
    const int lane = t & 63;
    const int wave = t >> 6;
    const int wm = (wave >> 1) * 32;
    const int wn = (wave & 1) * 32;
    const int2 bxy = xcd_swz();
    const int bm = bxy.x * 64;
    const int bn = bxy.y * 64;
    const int fr = lane & 15;
    const int quad = lane >> 4;

    v4f acc[2][2];
#pragma unroll
    for (int i = 0; i < 2; ++i)
#pragma unroll
        for (int j = 0; j < 2; ++j) { v4f z = {0.f, 0.f, 0.f, 0.f}; acc[i][j] = z; }

    auto stage = [&](int buf, int k0) {
#pragma unroll
        for (int r = 0; r < 2; ++r) {
            int c = t + 256 * r;
            int row = c >> 3;
            int g = (c & 7) ^ (row & 7);
            gll16(A + (size_t)(bm + row) * lda + k0 + g * 8, &As[buf][c * 8]);
            gll16(BT + (size_t)(bn + row) * K + k0 + g * 8, &Bs[buf][c * 8]);
        }
    };

    stage(0, 0);
    __syncthreads();
    const int nb = K >> 6;
    for (int kt = 0; kt < nb; ++kt) {
        const int buf = kt & 1;
        if (kt + 1 < nb) stage(buf ^ 1, (kt + 1) * 64);
#pragma unroll
        for (int ks = 0; ks < 2; ++ks) {
            v8bf af[2], bfr[2];
            const int gk = ((ks * 4 + quad) ^ (fr & 7)) * 8;
#pragma unroll
            for (int mt = 0; mt < 2; ++mt)
                af[mt] = *(const v8bf*)(&As[buf][(wm + mt * 16 + fr) * 64 + gk]);
#pragma unroll
            for (int nt = 0; nt < 2; ++nt)
                bfr[nt] = *(const v8bf*)(&Bs[buf][(wn + nt * 16 + fr) * 64 + gk]);
#pragma unroll
            for (int mt = 0; mt < 2; ++mt)
#pragma unroll
                for (int nt = 0; nt < 2; ++nt)
                    acc[mt][nt] = __builtin_amdgcn_mfma_f32_16x16x32_bf16(
                        af[mt], bfr[nt], acc[mt][nt], 0, 0, 0);
        }
        __syncthreads();
    }
    const int r0 = quad * 4;
#pragma unroll
    for (int mt = 0; mt < 2; ++mt)
#pragma unroll
        for (int nt = 0; nt < 2; ++nt)
#pragma unroll
            for (int r = 0; r < 4; ++r) {
                int row = bm + wm + mt * 16 + r0 + r;
                int col = bn + wn + nt * 16 + fr;
                if (f) ((float*)C)[(size_t)row * N + col] = acc[mt][nt][r];
                else   ((bf16*)C)[(size_t)row * N + col] = f2bf(acc[mt][nt][r]);
            }
}

// ---------------- transpose w/ separate z-strides ----------------------------
__global__ __launch_bounds__(256)
void transpose2_k(const void* __restrict__ in, bf16* __restrict__ out, int R, int C,
                  size_t inZ, size_t outZ, const int* __restrict__ flag)
{
    __shared__ bf16 tile[32][33];
    int f = *flag;
    size_t ioff = (size_t)blockIdx.z * inZ;
    bf16* dst = out + (size_t)blockIdx.z * outZ;
    int c0 = blockIdx.x * 32, r0 = blockIdx.y * 32;
    int tx = threadIdx.x, ty = threadIdx.y;
#pragma unroll
    for (int i = 0; i < 32; i += 8)
        tile[ty + i][tx] = f2bf(ldin(in, ioff + (size_t)(r0 + ty + i) * C + c0 + tx, f));
    __syncthreads();
#pragma unroll
    for (int i = 0; i < 32; i += 8)
        dst[(size_t)(c0 + ty + i) * R + r0 + tx] = tile[tx][ty + i];
}

// ---------------- W1 transpose with a/gate interleave permutation ------------
// out row j' for orig col j: j<2048 (a): j' = (j>>5)*64 + (j&31);
// j>=2048 (gate): j' = ((j-2048)>>5)*64 + 32 + (j&31).
__global__ __launch_bounds__(256)
void transposeW1_k(const void* __restrict__ in, bf16* __restrict__ out,
                   const int* __restrict__ flag)
{
    __shared__ bf16 tile[32][33];
    int f = *flag;
    size_t ioff = (size_t)blockIdx.z * (512ull * 4096);
    bf16* dst = out + (size_t)blockIdx.z * (512ull * 4096);
    int c0 = blockIdx.x * 32, r0 = blockIdx.y * 32;
    int tx = threadIdx.x, ty = threadIdx.y;
#pragma unroll
    for (int i = 0; i < 32; i += 8)
        tile[ty + i][tx] = f2bf(ldin(in, ioff + (size_t)(r0 + ty + i) * 4096 + c0 + tx, f));
    __syncthreads();
#pragma unroll
    for (int i = 0; i < 32; i += 8) {
        int j = c0 + ty + i;
        int jp = (j < 2048) ? (((j >> 5) << 6) | (j & 31))
                            : ((((j - 2048) >> 5) << 6) | 32 | (j & 31));
        dst[(size_t)jp * 512 + r0 + tx] = tile[tx][ty + i];
    }
}

// ---------------- x = in; xn = LN(x)*g  (one row per WAVE, no barriers) ------
__global__ __launch_bounds__(256)
void xinit_ln_k(const void* __restrict__ in, const void* __restrict__ g,
                const int* __restrict__ flag, float* __restrict__ x, bf16* __restrict__ xn)
{
    int f = *flag;
    int row = blockIdx.x * 4 + (threadIdx.x >> 6);
    int lane = threadIdx.x & 63;
    int c0 = lane * 8;
    float v[8];
    ld8(in, (size_t)row * 512 + c0, f, v);
    // persist x as f32
    float* xr = x + (size_t)row * 512 + c0;
    *(float4*)xr       = make_float4(v[0], v[1], v[2], v[3]);
    *(float4*)(xr + 4) = make_float4(v[4], v[5], v[6], v[7]);
    float s = 0.f;
#pragma unroll
    for (int j = 0; j < 8; ++j) s += v[j];
    float mean = wave_sum(s) * (1.f / 512.f);
    float q = 0.f;
#pragma unroll
    for (int j = 0; j < 8; ++j) { float d = v[j] - mean; q += d * d; }
    float var = wave_sum(q) * (1.f / 512.f);
    float rstd = rsqrtf(var + 1e-5f);
    float gv[8];
    ld8(g, c0, f, gv);
    v8bf o;
#pragma unroll
    for (int j = 0; j < 8; ++j) o[j] = tobf((v[j] - mean) * rstd * gv[j]);
    *(v8bf*)(xn + (size_t)row * 512 + c0) = o;
}

// ------ x += LN(t)*g1 ; xn = LN(x)*g2  (one row per WAVE, no barriers) -------
__global__ __launch_bounds__(256)
void addln_ln_k(const bf16* __restrict__ tin, const void* __restrict__ g1, int g1off,
                const void* __restrict__ g2, int g2off, const int* __restrict__ flag,
                float* __restrict__ x, bf16* __restrict__ xn)
{
    int f = *flag;
    int row = blockIdx.x * 4 + (threadIdx.x >> 6);
    int lane = threadIdx.x & 63;
    int c0 = lane * 8;
    float tv[8];
    {
        v8bf a = *(const v8bf*)(tin + (size_t)row * 512 + c0);
#pragma unroll
        for (int j = 0; j < 8; ++j) tv[j] = (float)a[j];
    }
    float s = 0.f;
#pragma unroll
    for (int j = 0; j < 8; ++j) s += tv[j];
    float mean = wave_sum(s) * (1.f / 512.f);
    float q = 0.f;
#pragma unroll
    for (int j = 0; j < 8; ++j) { float d = tv[j] - mean; q += d * d; }
    float var = wave_sum(q) * (1.f / 512.f);
    float rstd = rsqrtf(var + 1e-5f);
    float g1v[8];
    ld8(g1, (size_t)g1off + c0, f, g1v);
    float* xr = x + (size_t)row * 512 + c0;
    float4 xa = *(float4*)xr, xb = *(float4*)(xr + 4);
    float nx[8] = {xa.x, xa.y, xa.z, xa.w, xb.x, xb.y, xb.z, xb.w};
#pragma unroll
    for (int j = 0; j < 8; ++j) nx[j] += (tv[j] - mean) * rstd * g1v[j];
    *(float4*)xr       = make_float4(nx[0], nx[1], nx[2], nx[3]);
    *(float4*)(xr + 4) = make_float4(nx[4], nx[5], nx[6], nx[7]);
    float s2 = 0.f;
#pragma unroll
    for (int j = 0; j < 8; ++j) s2 += nx[j];
    float mean2 = wave_sum(s2) * (1.f / 512.f);
    float q2 = 0.f;
#pragma unroll
    for (int j = 0; j < 8; ++j) { float e = nx[j] - mean2; q2 += e * e; }
    float var2 = wave_sum(q2) * (1.f / 512.f);
    float rstd2 = rsqrtf(var2 + 1e-5f);
    float g2v[8];
    ld8(g2, (size_t)g2off + c0, f, g2v);
    v8bf o;
#pragma unroll
    for (int j = 0; j < 8; ++j) o[j] = tobf((nx[j] - mean2) * rstd2 * g2v[j]);
    *(v8bf*)(xn + (size_t)row * 512 + c0) = o;
}

// -- x += t ; xn = (stable? stableLN : LN)(x)*g  (one row per WAVE) -----------
__global__ __launch_bounds__(256)
void add_ln_k(const bf16* __restrict__ tin, const void* __restrict__ g, int goff,
              const int* __restrict__ flag, int stable,
              float* __restrict__ x, bf16* __restrict__ xn)
{
    int f = *flag;
    int row = blockIdx.x * 4 + (threadIdx.x >> 6);
    int lane = threadIdx.x & 63;
    int c0 = lane * 8;
    float nx[8];
    {
        v8bf a = *(const v8bf*)(tin + (size_t)row * 512 + c0);
        float* xr = x + (size_t)row * 512 + c0;
        float4 xa = *(float4*)xr, xb = *(float4*)(xr + 4);
        float xv[8] = {xa.x, xa.y, xa.z, xa.w, xb.x, xb.y, xb.z, xb.w};
#pragma unroll
        for (int j = 0; j < 8; ++j) nx[j] = xv[j] + (float)a[j];
        *(float4*)xr       = make_float4(nx[0], nx[1], nx[2], nx[3]);
        *(float4*)(xr + 4) = make_float4(nx[4], nx[5], nx[6], nx[7]);
    }
    float v[8];
#pragma unroll
    for (int j = 0; j < 8; ++j) v[j] = nx[j];
    if (stable) {
        float m = v[0];
#pragma unroll
        for (int j = 1; j < 8; ++j) m = fmaxf(m, v[j]);
        float mx = wave_max(m);
#pragma unroll
        for (int j = 0; j < 8; ++j) v[j] /= mx;
    }
    float s = 0.f;
#pragma unroll
    for (int j = 0; j < 8; ++j) s += v[j];
    float mean = wave_sum(s) * (1.f / 512.f);
    float q = 0.f;
#pragma unroll
    for (int j = 0; j < 8; ++j) { float d = v[j] - mean; q += d * d; }
    float var = wave_sum(q) * (1.f / 512.f);
    float rstd = rsqrtf(var + 1e-5f);
    float gv[8];
    ld8(g, (size_t)goff + c0, f, gv);
    v8bf o;
#pragma unroll
    for (int j = 0; j < 8; ++j) o[j] = tobf((v[j] - mean) * rstd * gv[j]);
    *(v8bf*)(xn + (size_t)row * 512 + c0) = o;
}

// ------- rel-pos bias table (pre-offset by -16) + rotary table, merged -------
// bias: qn,kn are l2-normalized to norm 4 => s = qn.kn <= 16 (Cauchy-Schwarz),
// |bias| << 1, so exp(s + bias - 16) <= ~1.11; softmax shift-invariance lets
// attention skip online-max tracking. rotary: tab[n*16+p] = (cos, sin).
__global__ __launch_bounds__(256)
void biasrot_k(const void* __restrict__ rpe, const int* __restrict__ flag,
               float* __restrict__ tab, float2* __restrict__ rtab)
{
    int idx = blockIdx.x * 256 + threadIdx.x;
    if (idx < 8 * 1025) {
        int f = *flag;
        int h = idx / 1025, dist = idx % 1025;
        int bkt;
        if (dist < 16) bkt = dist;
        else {
            bkt = 16 + (int)(logf((float)dist / 16.f) / logf(8.f) * 16.f);
            if (bkt > 31) bkt = 31;
        }
        tab[idx] = ldin(rpe, bkt * 8 + h, f) - 16.f;
    } else if (idx < 8 * 1025 + 16384) {
        int k = idx - 8 * 1025;
        int n = k >> 4, p = k & 15;
        float ang = (float)n * expf((float)p * -0.5756462732f);
        rtab[k] = make_float2(cosf(ang), sinf(ang));
    }
}

// ---------------- merged q + k/v prep (qkv stride 640, rotary via table) -----
// blocks [0,2048): q rows, 16 per block (4/wave, 16 lanes x 4 els each).
// blocks [2048,3200): k/v rows j in [0,1152) x b (4608, 4/block, 1/wave).
// K/Vt are padded to 1152 rows (zeros for j>=1025) so attention's 128-wide
// chunk loads never go out of bounds.
__global__ __launch_bounds__(256)
void qkvprep_k(const bf16* __restrict__ qkv, const void* __restrict__ nkv, int nkoff,
               const int* __restrict__ flag, const float2* __restrict__ rtab,
               bf16* __restrict__ Q, bf16* __restrict__ K, bf16* __restrict__ Vt)
{
    int t = threadIdx.x, lane = t & 63;
    int bid = blockIdx.x;
    if (bid < 2048) {
        int rid = bid * 16 + (t >> 4);            // one row per 16-lane group
        int h = rid & 7;
        int n = (rid >> 3) & 1023;
        int b = rid >> 13;
        int g16 = t & 15;
        int d0 = g16 * 4;
        v4bf a = *(const v4bf*)(qkv + (size_t)((b << 10) | n) * 640 + h * 64 + d0);
        float v[4];
#pragma unroll
        for (int j = 0; j < 4; ++j) v[j] = (float)a[j] * 16.f;
        if (d0 < 32) {                            // rotary, pairs in-lane
            float4 cs = *(const float4*)((const float*)rtab + (size_t)n * 32 + (size_t)(d0 >> 1) * 2);
            float r0 = v[0] * cs.x - v[1] * cs.y;
            float r1 = v[1] * cs.x + v[0] * cs.y;
            float r2 = v[2] * cs.z - v[3] * cs.w;
            float r3 = v[3] * cs.z + v[2] * cs.w;
            v[0] = r0; v[1] = r1; v[2] = r2; v[3] = r3;
        }
        float ss = v[0]*v[0] + v[1]*v[1] + v[2]*v[2] + v[3]*v[3];
#pragma unroll
        for (int o = 1; o < 16; o <<= 1) ss += __shfl_xor(ss, o, 64);
        float sc = 4.f / fmaxf(sqrtf(ss), 1e-12f);
        v4bf ov;
#pragma unroll
        for (int j = 0; j < 4; ++j) ov[j] = tobf(v[j] * sc);
        *(v4bf*)(Q + (((size_t)(b * 8 + h)) * 1024 + n) * 64 + d0) = ov;
    } else {
        int f = *flag;
        int rid = (bid - 2048) * 4 + (t >> 6);
        if (rid >= 4 * 1152) return;
        int j = rid % 1152;
        int b = rid / 1152;
        if (j >= 1025) {
            K[((size_t)b * 1152 + j) * 64 + lane] = f2bf(0.f);
            Vt[((size_t)b * 64 + lane) * 1152 + j] = f2bf(0.f);
            return;
        }
        float kv, vv;
        if (j == 0) {
            kv = ldin(nkv, nkoff + lane, f);
            vv = ldin(nkv, nkoff + 64 + lane, f);
        } else {
            int n = j - 1;
            const bf16* src = qkv + (size_t)(b * 1024 + n) * 640 + 512;
            kv = bf2f(src[lane]);
            vv = bf2f(src[64 + lane]);
            if (lane < 32) {
                float2 cs = rtab[n * 16 + (lane >> 1)];
                float other = __shfl_xor(kv, 1, 64);
                float rot = (lane & 1) ? other : -other;
                kv = kv * cs.x + rot * cs.y;
            }
        }
        float nrm = sqrtf(wave_sum(kv * kv));
        kv = kv / fmaxf(nrm, 1e-12f) * 4.f;
        K[((size_t)b * 1152 + j) * 64 + lane] = f2bf(kv);
        Vt[((size_t)b * 64 + lane) * 1152 + j] = f2bf(vv);
    }
}

// -------- MFMA flash attention, KVBLK=128, NO SPLIT, FIXED-MAX softmax -------
// grid (B*H=32, 16 qtiles), block 256 = 4 waves (16 q-rows each). K/Vt padded
// to 1152 rows so the last chunk's register prefetch stays in-bounds. Bias
// table pre-offset by -16 => p = exp(s + bias'), no online max; l reduced once
// at the end; output normalized in-register and written directly.
__global__ __launch_bounds__(256)
void attn_mfma(const bf16* __restrict__ Q, const bf16* __restrict__ Kg,
               const bf16* __restrict__ Vtg, const float* __restrict__ bias,
               bf16* __restrict__ O)
{
    __shared__ bf16 Ks[128][72];
    __shared__ bf16 Vts[64][136];
    __shared__ bf16 Ps[4][16][136];
    __shared__ float bs[1088];
    const int bh = blockIdx.x, b = bh >> 3, h = bh & 7;
    const int yy = (int)gridDim.y - 1 - (int)blockIdx.y;   // longest first
    const int i0 = yy * 64;
    const int t = threadIdx.x, lane = t & 63, w = t >> 6;
    const int col = lane & 15, quad = lane >> 4, fk = quad * 8;
    const float* bt = bias + h * 1025;
    const bf16* Kb = Kg + (size_t)b * 1152 * 64;
    const bf16* Vb = Vtg + (size_t)b * 64 * 1152;

    // stage bias row into LDS: dist range needed is [0, i0+63]
    for (int idx = t; idx < i0 + 64; idx += 256) bs[idx] = bt[idx];

    v8bf qf[2];
    const bf16* qrow = Q + ((size_t)bh * 1024 + i0 + w * 16 + col) * 64;
    qf[0] = *(const v8bf*)(qrow + fk);
    qf[1] = *(const v8bf*)(qrow + 32 + fk);

    v4f oacc[4];
#pragma unroll
    for (int dt = 0; dt < 4; ++dt) { v4f z = {0.f,0.f,0.f,0.f}; oacc[dt] = z; }
    float lpart[4] = {0.f, 0.f, 0.f, 0.f};

    // chunks of 128 covering j in [0, i0+65]
    const int nch = (i0 + 66 + 127) >> 7;
    const int rK = t >> 3,  cK = (t & 7) * 8;    // K granule coords (+32 rows/rep)
    const int rV = t >> 4,  cV = (t & 15) * 8;   // Vt granule coords (+16 rows/rep)

    v8bf kr[4], vr[4];
#pragma unroll
    for (int r = 0; r < 4; ++r) {
        kr[r] = *(const v8bf*)(Kb + (size_t)(rK + 32 * r) * 64 + cK);
        vr[r] = *(const v8bf*)(Vb + (size_t)(rV + 16 * r) * 1152 + cV);
    }

    for (int ch = 0; ch < nch; ++ch) {
        const int j0 = ch * 128;
        __syncthreads();                                 // prev compute done w/ LDS
#pragma unroll
        for (int r = 0; r < 4; ++r) {
            *(v8bf*)(&Ks[rK + 32 * r][cK])  = kr[r];
            *(v8bf*)(&Vts[rV + 16 * r][cV]) = vr[r];
        }
        if (ch + 1 < nch) {                              // prefetch next chunk
            int j0n = (ch + 1) * 128;
#pragma unroll
            for (int r = 0; r < 4; ++r) {
                kr[r] = *(const v8bf*)(Kb + (size_t)(j0n + rK + 32 * r) * 64 + cK);
                vr[r] = *(const v8bf*)(Vb + (size_t)(rV + 16 * r) * 1152 + j0n + cV);
            }
        }
        __syncthreads();

        // QK^T (8 col-tiles of 16)
        v4f sreg[8];
#pragma unroll
        for (int nt = 0; nt < 8; ++nt) {
            v4f z = {0.f,0.f,0.f,0.f};
            v8bf kf0 = *(const v8bf*)(&Ks[nt * 16 + col][fk]);
            v8bf kf1 = *(const v8bf*)(&Ks[nt * 16 + col][32 + fk]);
            z = __builtin_amdgcn_mfma_f32_16x16x32_bf16(qf[0], kf0, z, 0, 0, 0);
            z = __builtin_amdgcn_mfma_f32_16x16x32_bf16(qf[1], kf1, z, 0, 0, 0);
            sreg[nt] = z;
        }

        // p = exp(s + bias - 16); no max tracking, no cross-lane ops.
        if (j0 + 127 <= i0) {
            // fully-interior chunk: no causal/pad mask, dist >= 0 guaranteed
#pragma unroll
            for (int reg = 0; reg < 4; ++reg) {
                int i = i0 + w * 16 + quad * 4 + reg;
                int dbase = i - j0 - col;
#pragma unroll
                for (int nt = 0; nt < 8; ++nt) {
                    float pp = __expf(sreg[nt][reg] + bs[dbase - nt * 16]);
                    lpart[reg] += pp;
                    Ps[w][quad * 4 + reg][nt * 16 + col] = f2bf(pp);
                }
            }
        } else {
#pragma unroll
            for (int reg = 0; reg < 4; ++reg) {
                int i = i0 + w * 16 + quad * 4 + reg;
#pragma unroll
                for (int nt = 0; nt < 8; ++nt) {
                    int j = j0 + nt * 16 + col;
                    float pp = 0.f;
                    if (j <= i + 1 && j < 1025) {
                        int dist = i - j; if (dist < 0) dist = 0;
                        pp = __expf(sreg[nt][reg] + bs[dist]);
                    }
                    lpart[reg] += pp;
                    Ps[w][quad * 4 + reg][nt * 16 + col] = f2bf(pp);
                }
            }
        }

        // PV: 4 k-slot groups of 32
        v8bf pf[4];
#pragma unroll
        for (int ks = 0; ks < 4; ++ks)
            pf[ks] = *(const v8bf*)(&Ps[w][col][ks * 32 + fk]);
#pragma unroll
        for (int dt = 0; dt < 4; ++dt) {
#pragma unroll
            for (int ks = 0; ks < 4; ++ks) {
                v8bf vf = *(const v8bf*)(&Vts[dt * 16 + col][ks * 32 + fk]);
                oacc[dt] = __builtin_amdgcn_mfma_f32_16x16x32_bf16(pf[ks], vf, oacc[dt], 0, 0, 0);
            }
        }
    }

    // single deferred l reduction (16 cols per row) + normalized direct write
#pragma unroll
    for (int reg = 0; reg < 4; ++reg) {
#pragma unroll
        for (int o = 1; o < 16; o <<= 1) lpart[reg] += __shfl_xor(lpart[reg], o, 64);
        float inv = 1.f / lpart[reg];
        int i = i0 + w * 16 + quad * 4 + reg;
        bf16* orow = O + ((size_t)(b * 1024 + i)) * 512 + h * 64;
#pragma unroll
        for (int dt = 0; dt < 4; ++dt)
            orow[dt * 16 + col] = f2bf(oacc[dt][reg] * inv);
    }
}

// =============================================================================
extern "C" void kernel_launch(void* const* d_in, const int* in_sizes, int n_in,
                              void* d_out, int out_size, void* d_ws, size_t ws_size,
                              hipStream_t stream)
{
    const void* x_in     = d_in[0];
    const void* rpe      = d_in[1];
    const void* g_attn   = d_in[2];
    const void* null_kv  = d_in[3];
    const void* Wq       = d_in[4];
    const void* Wkv      = d_in[5];
    const void* Wo       = d_in[6];
    const void* g_attn_o = d_in[7];
    const void* g_ff     = d_in[8];
    const void* W1       = d_in[9];
    const void* W2       = d_in[10];
    const void* g_final  = d_in[11];
    const void* W_proj   = d_in[12];

    char* wp = (char*)d_ws;
    auto alloc = [&](size_t bytes) {
        char* p = wp; wp += (bytes + 255) & ~(size_t)255; return p;
    };
    float* xf    = (float*)alloc(4096ull * 512 * 4);
    bf16*  xn    = (bf16*) alloc(4096ull * 512 * 2);
    bf16*  tb    = (bf16*) alloc(4096ull * 512 * 2);
    bf16*  ub    = (bf16*) alloc(4096ull * 4096 * 2);
    bf16*  Kb    = (bf16*) alloc(4ull * 1152 * 64 * 2);
    bf16*  Vtb   = (bf16*) alloc(4ull * 64 * 1152 * 2);
    float* btab  = (float*)alloc(8ull * 1025 * 4);
    float2* rtab = (float2*)alloc(16384ull * 8);
    int*   dfl   = (int*)  alloc(256);
    bf16*  WqkvT = (bf16*) alloc(6ull * 640 * 512 * 2);
    bf16*  WoT   = (bf16*) alloc(6ull * 512 * 512 * 2);
    bf16*  W1T   = (bf16*) alloc(6ull * 4096 * 512 * 2);
    bf16*  W2T   = (bf16*) alloc(6ull * 512 * 2048 * 2);
    bf16*  WpT   = (bf16*) alloc(512ull * 512 * 2);
    // aliased into ub (16,777,216 elems; all dead before gemm256_silu writes ub)
    bf16*  qkvb  = ub;                        // 2,621,440 elems
    bf16*  Qb    = ub + 2621440;              // 2,097,152
    bf16*  ob    = ub + 4718592;              // 2,097,152

    detect_k<<<1, 256, 0, stream>>>((const unsigned short*)x_in, dfl);
    transpose2_k<<<dim3(16, 16, 6),  dim3(32, 8), 0, stream>>>(Wq, WqkvT, 512, 512, 512ull*512, 640ull*512, dfl);
    transpose2_k<<<dim3(4, 16, 6),   dim3(32, 8), 0, stream>>>(Wkv, WqkvT + 512ull*512, 512, 128, 512ull*128, 640ull*512, dfl);
    transpose2_k<<<dim3(16, 16, 6),  dim3(32, 8), 0, stream>>>(Wo, WoT, 512, 512, 512ull*512, 512ull*512, dfl);
    transposeW1_k<<<dim3(128, 16, 6), dim3(32, 8), 0, stream>>>(W1, W1T, dfl);
    transpose2_k<<<dim3(16, 64, 6),  dim3(32, 8), 0, stream>>>(W2, W2T, 2048, 512, 2048ull*512, 2048ull*512, dfl);
    transpose2_k<<<dim3(16, 16, 1),  dim3(32, 8), 0, stream>>>(W_proj, WpT, 512, 512, 512ull*512, 512ull*512, dfl);
    biasrot_k<<<97, 256, 0, stream>>>(rpe, dfl, btab, rtab);
    xinit_ln_k<<<1024, 256, 0, stream>>>(x_in, g_attn, dfl, xf, xn);

    for (int l = 0; l < 6; ++l) {
        gemm64<<<dim3(64, 10), 256, 0, stream>>>(xn, WqkvT + (size_t)l * 640 * 512, qkvb, 4096, 640, 512, 512);
        qkvprep_k<<<3200, 256, 0, stream>>>(qkvb, null_kv, l * 128, dfl, rtab, Qb, Kb, Vtb);
        attn_mfma<<<dim3(32, 16), 256, 0, stream>>>(Qb, Kb, Vtb, btab, ob);
        gemm64<<<dim3(64, 8), 256, 0, stream>>>(ob, WoT + (size_t)l * 512 * 512, tb, 4096, 512, 512, 512);
        addln_ln_k<<<1024, 256, 0, stream>>>(tb, g_attn_o, l * 512, g_ff, l * 512, dfl, xf, xn);
        gemm256_silu<<<dim3(16, 16), 512, 0, stream>>>(xn, W1T + (size_t)l * 4096 * 512, ub, 512, 512);
        gemm64<<<dim3(64, 8), 256, 0, stream>>>(ub, W2T + (size_t)l * 512 * 2048, tb, 4096, 512, 2048, 2048);
        if (l < 5)
            add_ln_k<<<1024, 256, 0, stream>>>(tb, g_attn, (l + 1) * 512, dfl, 0, xf, xn);
        else
            add_ln_k<<<1024, 256, 0, stream>>>(tb, g_final, 0, dfl, 1, xf, xn);
    }
    gemm64_out<<<dim3(64, 8), 256, 0, stream>>>(xn, WpT, d_out, 4096, 512, 512, 512, dfl);
}

// Round 10
// 798.738 us; speedup vs baseline: 1.0322x; 1.0322x over previous
//
#include <hip/hip_runtime.h>
#include <hip/hip_bf16.h>
#include <cmath>

using bf16 = __hip_bfloat16;
typedef __bf16 v8bf __attribute__((ext_vector_type(8)));
typedef __bf16 v4bf __attribute__((ext_vector_type(4)));
typedef float  v4f  __attribute__((ext_vector_type(4)));

__device__ __forceinline__ float bf2f(bf16 x) { return __bfloat162float(x); }
__device__ __forceinline__ bf16  f2bf(float x) { return __float2bfloat16(x); }
__device__ __forceinline__ __bf16 tobf(float x) {
    bf16 h = __float2bfloat16(x);
    return __builtin_bit_cast(__bf16, h);
}

// async global->LDS, 16B per lane (lds dest = wave-uniform base + lane*16)
__device__ __forceinline__ void gll16(const bf16* g, bf16* l) {
    __builtin_amdgcn_global_load_lds(
        (const __attribute__((address_space(1))) unsigned int*)g,
        (__attribute__((address_space(3))) unsigned int*)l, 16, 0, 0);
}

// NOTE: T1 XCD-aware block swizzle was tried (round 9) and REGRESSED ~1.5%:
// all working sets here are L3-resident, and measured behavior is "costs ~2%
// when L3-fit" (m160). Do not re-add for this problem size.

__device__ __forceinline__ float ldin(const void* p, size_t i, int isf32) {
    if (isf32) return ((const float*)p)[i];
    return bf2f(((const bf16*)p)[i]);
}

// flag-dtype vector load of 8 consecutive elements
__device__ __forceinline__ void ld8(const void* p, size_t base, int f, float v[8]) {
    if (f) {
        const float* pf = (const float*)p + base;
        float4 a = *(const float4*)pf, b = *(const float4*)(pf + 4);
        v[0]=a.x; v[1]=a.y; v[2]=a.z; v[3]=a.w;
        v[4]=b.x; v[5]=b.y; v[6]=b.z; v[7]=b.w;
    } else {
        v8bf a = *(const v8bf*)((const bf16*)p + base);
#pragma unroll
        for (int j = 0; j < 8; ++j) v[j] = (float)a[j];
    }
}

__device__ __forceinline__ float wave_sum(float v) {
#pragma unroll
    for (int o = 32; o > 0; o >>= 1) v += __shfl_xor(v, o, 64);
    return v;
}
__device__ __forceinline__ float wave_max(float v) {
#pragma unroll
    for (int o = 32; o > 0; o >>= 1) v = fmaxf(v, __shfl_xor(v, o, 64));
    return v;
}

// ---------------- dtype detector -------------------------------------------
__global__ void detect_k(const unsigned short* __restrict__ x, int* __restrict__ flag)
{
    __shared__ int s;
    int t = threadIdx.x;
    if (t == 0) s = 0;
    __syncthreads();
    int bad = 0;
    for (int i = t; i < 4096; i += 256) {
        int e = (x[i] >> 7) & 0xFF;
        if (e >= 147) bad++;
    }
    atomicAdd(&s, bad);
    __syncthreads();
    if (t == 0) *flag = (s > 64) ? 1 : 0;
}

// ============ FUSED PROLOGUE: all weight transposes + tables + xinit-LN ======
// Everything after detect_k is mutually independent (all read only the flag +
// their own input), so one kernel segmented by block range replaces 8
// serialized launches: small transposes execute concurrently under W1's big
// one, and 7 launch gaps + grid tails disappear.
// Segments (256-thread blocks, shaped (32,8)):
//  [0,1536)        Wq   512x512  x6 -> WqkvT (outZ 640*512)
//  [1536,1920)     Wkv  512x128  x6 -> WqkvT+512*512
//  [1920,3456)     Wo   512x512  x6 -> WoT
//  [3456,15744)    W1   512x4096 x6 -> W1T with a/gate interleave permutation:
//                  j<2048: j'=(j>>5)*64+(j&31); else j'=((j-2048)>>5)*64+32+(j&31)
//  [15744,21888)   W2   2048x512 x6 -> W2T
//  [21888,22144)   Wp   512x512  x1 -> WpT
//  [22144,22241)   bias table (pre-offset -16; see attn) + rotary cos/sin
//  [22241,23265)   x = in; xn = LN(x)*g   (one row per wave)
__global__ __launch_bounds__(256)
void prologue_k(const void* __restrict__ Wq, const void* __restrict__ Wkv,
                const void* __restrict__ Wo, const void* __restrict__ W1,
                const void* __restrict__ W2, const void* __restrict__ Wp,
                const void* __restrict__ rpe, const void* __restrict__ x_in,
                const void* __restrict__ g_attn, const int* __restrict__ flag,
                bf16* __restrict__ WqkvT, bf16* __restrict__ WoT,
                bf16* __restrict__ W1T, bf16* __restrict__ W2T,
                bf16* __restrict__ WpT, float* __restrict__ btab,
                float2* __restrict__ rtab, float* __restrict__ xf,
                bf16* __restrict__ xn)
{
    __shared__ bf16 tile[32][33];
    const int bb = blockIdx.x;
    const int tx = threadIdx.x, ty = threadIdx.y;
    const int flat = ty * 32 + tx;
    const int T0 = 1536, T1 = T0 + 384, T2 = T1 + 1536, T3 = T2 + 12288,
              T4 = T3 + 6144, T5 = T4 + 256, T6 = T5 + 97;
    if (bb < T5) {
        const void* in; bf16* out; int nx, ny, R, C, lb, w1 = 0;
        size_t inZ, outZ;
        if (bb < T0)      { in=Wq;  out=WqkvT;            nx=16;  ny=16; R=512;  C=512;  inZ=512ull*512;  outZ=640ull*512;  lb=bb; }
        else if (bb < T1) { in=Wkv; out=WqkvT+512ull*512; nx=4;   ny=16; R=512;  C=128;  inZ=512ull*128;  outZ=640ull*512;  lb=bb-T0; }
        else if (bb < T2) { in=Wo;  out=WoT;              nx=16;  ny=16; R=512;  C=512;  inZ=512ull*512;  outZ=512ull*512;  lb=bb-T1; }
        else if (bb < T3) { in=W1;  out=W1T;              nx=128; ny=16; R=512;  C=4096; inZ=512ull*4096; outZ=512ull*4096; lb=bb-T2; w1=1; }
        else if (bb < T4) { in=W2;  out=W2T;              nx=16;  ny=64; R=2048; C=512;  inZ=2048ull*512; outZ=2048ull*512; lb=bb-T3; }
        else              { in=Wp;  out=WpT;              nx=16;  ny=16; R=512;  C=512;  inZ=512ull*512;  outZ=512ull*512;  lb=bb-T4; }
        int f = *flag;
        int bx = lb % nx, rem = lb / nx, by = rem % ny, bz = rem / ny;
        size_t ioff = (size_t)bz * inZ;
        bf16* dst = out + (size_t)bz * outZ;
        int c0 = bx * 32, r0 = by * 32;
#pragma unroll
        for (int i = 0; i < 32; i += 8)
            tile[ty + i][tx] = f2bf(ldin(in, ioff + (size_t)(r0 + ty + i) * C + c0 + tx, f));
        __syncthreads();
        if (!w1) {
#pragma unroll
            for (int i = 0; i < 32; i += 8)
                dst[(size_t)(c0 + ty + i) * R + r0 + tx] = tile[tx][ty + i];
        } else {
#pragma unroll
            for (int i = 0; i < 32; i += 8) {
                int j = c0 + ty + i;
                int jp = (j < 2048) ? (((j >> 5) << 6) | (j & 31))
                                    : ((((j - 2048) >> 5) << 6) | 32 | (j & 31));
                dst[(size_t)jp * 512 + r0 + tx] = tile[tx][ty + i];
            }
        }
    } else if (bb < T6) {
        int idx = (bb - T5) * 256 + flat;
        if (idx < 8 * 1025) {
            int f = *flag;
            int h = idx / 1025, dist = idx % 1025;
            int bkt;
            if (dist < 16) bkt = dist;
            else {
                bkt = 16 + (int)(logf((float)dist / 16.f) / logf(8.f) * 16.f);
                if (bkt > 31) bkt = 31;
            }
            btab[idx] = ldin(rpe, bkt * 8 + h, f) - 16.f;
        } else if (idx < 8 * 1025 + 16384) {
            int k = idx - 8 * 1025;
            int n = k >> 4, p = k & 15;
            float ang = (float)n * expf((float)p * -0.5756462732f);
            rtab[k] = make_float2(cosf(ang), sinf(ang));
        }
    } else {
        int f = *flag;
        int row = (bb - T6) * 4 + (flat >> 6);
        int lane = flat & 63;
        int c0 = lane * 8;
        float v[8];
        ld8(x_in, (size_t)row * 512 + c0, f, v);
        float* xr = xf + (size_t)row * 512 + c0;
        *(float4*)xr       = make_float4(v[0], v[1], v[2], v[3]);
        *(float4*)(xr + 4) = make_float4(v[4], v[5], v[6], v[7]);
        float s = 0.f;
#pragma unroll
        for (int j = 0; j < 8; ++j) s += v[j];
        float mean = wave_sum(s) * (1.f / 512.f);
        float q = 0.f;
#pragma unroll
        for (int j = 0; j < 8; ++j) { float d = v[j] - mean; q += d * d; }
        float var = wave_sum(q) * (1.f / 512.f);
        float rstd = rsqrtf(var + 1e-5f);
        float gv[8];
        ld8(g_attn, c0, f, gv);
        v8bf o;
#pragma unroll
        for (int j = 0; j < 8; ++j) o[j] = tobf((v[j] - mean) * rstd * gv[j]);
        *(v8bf*)(xn + (size_t)row * 512 + c0) = o;
    }
}

// ============ 256x256 / BK=64 / 8-wave double-buffered GEMM + SiLU ===========
// 2-phase pipeline: stage K-tile t+1 into buf^1 (async global_load_lds) BEFORE
// computing K-tile t from buf; the single __syncthreads() per tile drains
// vmcnt (stage complete) + lgkmcnt (reads complete).
// Swizzle (both-sides, rule #21): 16B-granule g within a 128B row is stored at
// linear LDS slot but sourced from global granule g^(row&7); ds_read applies
// the same XOR.
// BT is the PERMUTED W1^T (a/gate interleave): acc[mt][nt] (nt<2) pairs with
// acc[mt][nt+2] as (a, gate). U is 4096x2048.
__global__ __launch_bounds__(512, 2)
void gemm256_silu(const bf16* __restrict__ A, const bf16* __restrict__ BT,
                  bf16* __restrict__ U, int K, int lda)
{
    __shared__ bf16 As[2][256 * 64];
    __shared__ bf16 Bs[2][256 * 64];
    const int t = threadIdx.x;            // 0..511
    const int lane = t & 63;
    const int wave = t >> 6;              // 0..7  (2 M x 4 N)
    const int wm = (wave >> 2) * 128;
    const int wn = (wave & 3) * 64;
    const int bm = blockIdx.x * 256;
    const int bn = blockIdx.y * 256;
    const int fr = lane & 15;
    const int quad = lane >> 4;

    v4f acc[8][4];
#pragma unroll
    for (int i = 0; i < 8; ++i)
#pragma unroll
        for (int j = 0; j < 4; ++j) { v4f z = {0.f, 0.f, 0.f, 0.f}; acc[i][j] = z; }

    auto stage = [&](int buf, int k0) {
#pragma unroll
        for (int r = 0; r < 4; ++r) {
            int c = t + 512 * r;
            int row = c >> 3;
            int g = (c & 7) ^ (row & 7);
            gll16(A + (size_t)(bm + row) * lda + k0 + g * 8, &As[buf][c * 8]);
            gll16(BT + (size_t)(bn + row) * K + k0 + g * 8, &Bs[buf][c * 8]);
        }
    };

    stage(0, 0);
    __syncthreads();
    const int nb = K >> 6;                 // K/64 tiles
    for (int kt = 0; kt < nb; ++kt) {
        const int buf = kt & 1;
        if (kt + 1 < nb) stage(buf ^ 1, (kt + 1) * 64);
#pragma unroll
        for (int ks = 0; ks < 2; ++ks) {
            v8bf af[8], bfr[4];
            const int gk = ((ks * 4 + quad) ^ (fr & 7)) * 8;
#pragma unroll
            for (int mt = 0; mt < 8; ++mt)
                af[mt] = *(const v8bf*)(&As[buf][(wm + mt * 16 + fr) * 64 + gk]);
#pragma unroll
            for (int nt = 0; nt < 4; ++nt)
                bfr[nt] = *(const v8bf*)(&Bs[buf][(wn + nt * 16 + fr) * 64 + gk]);
#pragma unroll
            for (int mt = 0; mt < 8; ++mt)
#pragma unroll
                for (int nt = 0; nt < 4; ++nt)
                    acc[mt][nt] = __builtin_amdgcn_mfma_f32_16x16x32_bf16(
                        af[mt], bfr[nt], acc[mt][nt], 0, 0, 0);
        }
        __syncthreads();                   // drains stage (vmcnt) + reads done
    }

    const int r0 = quad * 4;
    const int gbase = ((bn + wn) >> 6) * 32;
#pragma unroll
    for (int mt = 0; mt < 8; ++mt)
#pragma unroll
        for (int nt = 0; nt < 2; ++nt)
#pragma unroll
            for (int r = 0; r < 4; ++r) {
                int row = bm + wm + mt * 16 + r0 + r;
                int col = gbase + nt * 16 + fr;
                float a  = acc[mt][nt][r];
                float gg = acc[mt][nt + 2][r];
                U[(size_t)row * 2048 + col] = f2bf(a * (gg / (1.f + __expf(-gg))));
            }
}

// ========= MFMA GEMM 64x64 / BK=64 double-buffered (async LDS staging) =======
// Tile 64x64 so the grid doubles (512-640 blocks = 2-2.5 blocks/CU):
// cross-block wave overlap (m114) hides the per-tile barrier drain.
// Swizzle identical to gemm256_silu (granule g ^ (row&7), both sides).
__global__ __launch_bounds__(256)
void gemm64(const bf16* __restrict__ A, const bf16* __restrict__ BT,
            bf16* __restrict__ C, int M, int N, int K, int lda)
{
    __shared__ bf16 As[2][64 * 64];
    __shared__ bf16 Bs[2][64 * 64];
    const int t = threadIdx.x;
    const int lane = t & 63;
    const int wave = t >> 6;
    const int wm = (wave >> 1) * 32;
    const int wn = (wave & 1) * 32;
    const int bm = blockIdx.x * 64;
    const int bn = blockIdx.y * 64;
    const int fr = lane & 15;
    const int quad = lane >> 4;

    v4f acc[2][2];
#pragma unroll
    for (int i = 0; i < 2; ++i)
#pragma unroll
        for (int j = 0; j < 2; ++j) { v4f z = {0.f, 0.f, 0.f, 0.f}; acc[i][j] = z; }

    auto stage = [&](int buf, int k0) {
#pragma unroll
        for (int r = 0; r < 2; ++r) {            // A,B: 64x64 = 512 granules each
            int c = t + 256 * r;
            int row = c >> 3;
            int g = (c & 7) ^ (row & 7);
            gll16(A + (size_t)(bm + row) * lda + k0 + g * 8, &As[buf][c * 8]);
            gll16(BT + (size_t)(bn + row) * K + k0 + g * 8, &Bs[buf][c * 8]);
        }
    };

    stage(0, 0);
    __syncthreads();
    const int nb = K >> 6;
    for (int kt = 0; kt < nb; ++kt) {
        const int buf = kt & 1;
        if (kt + 1 < nb) stage(buf ^ 1, (kt + 1) * 64);
#pragma unroll
        for (int ks = 0; ks < 2; ++ks) {
            v8bf af[2], bfr[2];
            const int gk = ((ks * 4 + quad) ^ (fr & 7)) * 8;
#pragma unroll
            for (int mt = 0; mt < 2; ++mt)
                af[mt] = *(const v8bf*)(&As[buf][(wm + mt * 16 + fr) * 64 + gk]);
#pragma unroll
            for (int nt = 0; nt < 2; ++nt)
                bfr[nt] = *(const v8bf*)(&Bs[buf][(wn + nt * 16 + fr) * 64 + gk]);
#pragma unroll
            for (int mt = 0; mt < 2; ++mt)
#pragma unroll
                for (int nt = 0; nt < 2; ++nt)
                    acc[mt][nt] = __builtin_amdgcn_mfma_f32_16x16x32_bf16(
                        af[mt], bfr[nt], acc[mt][nt], 0, 0, 0);
        }
        __syncthreads();
    }
    const int r0 = quad * 4;
#pragma unroll
    for (int mt = 0; mt < 2; ++mt)
#pragma unroll
        for (int nt = 0; nt < 2; ++nt)
#pragma unroll
            for (int r = 0; r < 4; ++r) {
                int row = bm + wm + mt * 16 + r0 + r;
                int col = bn + wn + nt * 16 + fr;
                C[(size_t)row * N + col] = f2bf(acc[mt][nt][r]);
            }
}

// ---- gemm64 (64x64, BK=64 dbuf) with flag-selected output dtype -------------
__global__ __launch_bounds__(256)
void gemm64_out(const bf16* __restrict__ A, const bf16* __restrict__ BT,
                void* __restrict__ C, int M, int N, int K, int lda,
                const int* __restrict__ flag)
{
    __shared__ bf16 As[2][64 * 64];
    __shared__ bf16 Bs[2][64 * 64];
    const int f = *flag;
    const int t = threadIdx.x;
    const int lane = t & 63;
    const int wave = t >> 6;
    const int wm = (wave >> 1) * 32;
    const int wn = (wave & 1) * 32;
    const int bm = blockIdx.x * 64;
    const int bn = blockIdx.y * 64;
    const int fr = lane & 15;
    const int quad = lane >> 4;

    v4f acc[2][2];
#pragma unroll
    for (int i = 0; i < 2; ++i)
#pragma unroll
        for (int j = 0; j < 2; ++j) { v4f z = {0.f, 0.f, 0.f, 0.f}; acc[i][j] = z; }

    auto stage = [&](int buf, int k0) {
#pragma unroll
        for (int r = 0; r < 2; ++r) {
            int c = t + 256 * r;
            int row = c >> 3;
            int g = (c & 7) ^ (row & 7);
            gll16(A + (size_t)(bm + row) * lda + k0 + g * 8, &As[buf][c * 8]);
            gll16(BT + (size_t)(bn + row) * K + k0 + g * 8, &Bs[buf][c * 8]);
        }
    };

    stage(0, 0);
    __syncthreads();
    const int nb = K >> 6;
    for (int kt = 0; kt < nb; ++kt) {
        const int buf = kt & 1;
        if (kt + 1 < nb) stage(buf ^ 1, (kt + 1) * 64);
#pragma unroll
        for (int ks = 0; ks < 2; ++ks) {
            v8bf af[2], bfr[2];
            const int gk = ((ks * 4 + quad) ^ (fr & 7)) * 8;
#pragma unroll
            for (int mt = 0; mt < 2; ++mt)
                af[mt] = *(const v8bf*)(&As[buf][(wm + mt * 16 + fr) * 64 + gk]);
#pragma unroll
            for (int nt = 0; nt < 2; ++nt)
                bfr[nt] = *(const v8bf*)(&Bs[buf][(wn + nt * 16 + fr) * 64 + gk]);
#pragma unroll
            for (int mt = 0; mt < 2; ++mt)
#pragma unroll
                for (int nt = 0; nt < 2; ++nt)
                    acc[mt][nt] = __builtin_amdgcn_mfma_f32_16x16x32_bf16(
                        af[mt], bfr[nt], acc[mt][nt], 0, 0, 0);
        }
        __syncthreads();
    }
    const int r0 = quad * 4;
#pragma unroll
    for (int mt = 0; mt < 2; ++mt)
#pragma unroll
        for (int nt = 0; nt < 2; ++nt)
#pragma unroll
            for (int r = 0; r < 4; ++r) {
                int row = bm + wm + mt * 16 + r0 + r;
                int col = bn + wn + nt * 16 + fr;
                if (f) ((float*)C)[(size_t)row * N + col] = acc[mt][nt][r];
                else   ((bf16*)C)[(size_t)row * N + col] = f2bf(acc[mt][nt][r]);
            }
}

// ------ x += LN(t)*g1 ; xn = LN(x)*g2  (one row per WAVE, no barriers) -------
__global__ __launch_bounds__(256)
void addln_ln_k(const bf16* __restrict__ tin, const void* __restrict__ g1, int g1off,
                const void* __restrict__ g2, int g2off, const int* __restrict__ flag,
                float* __restrict__ x, bf16* __restrict__ xn)
{
    int f = *flag;
    int row = blockIdx.x * 4 + (threadIdx.x >> 6);
    int lane = threadIdx.x & 63;
    int c0 = lane * 8;
    float tv[8];
    {
        v8bf a = *(const v8bf*)(tin + (size_t)row * 512 + c0);
#pragma unroll
        for (int j = 0; j < 8; ++j) tv[j] = (float)a[j];
    }
    float s = 0.f;
#pragma unroll
    for (int j = 0; j < 8; ++j) s += tv[j];
    float mean = wave_sum(s) * (1.f / 512.f);
    float q = 0.f;
#pragma unroll
    for (int j = 0; j < 8; ++j) { float d = tv[j] - mean; q += d * d; }
    float var = wave_sum(q) * (1.f / 512.f);
    float rstd = rsqrtf(var + 1e-5f);
    float g1v[8];
    ld8(g1, (size_t)g1off + c0, f, g1v);
    float* xr = x + (size_t)row * 512 + c0;
    float4 xa = *(float4*)xr, xb = *(float4*)(xr + 4);
    float nx[8] = {xa.x, xa.y, xa.z, xa.w, xb.x, xb.y, xb.z, xb.w};
#pragma unroll
    for (int j = 0; j < 8; ++j) nx[j] += (tv[j] - mean) * rstd * g1v[j];
    *(float4*)xr       = make_float4(nx[0], nx[1], nx[2], nx[3]);
    *(float4*)(xr + 4) = make_float4(nx[4], nx[5], nx[6], nx[7]);
    float s2 = 0.f;
#pragma unroll
    for (int j = 0; j < 8; ++j) s2 += nx[j];
    float mean2 = wave_sum(s2) * (1.f / 512.f);
    float q2 = 0.f;
#pragma unroll
    for (int j = 0; j < 8; ++j) { float e = nx[j] - mean2; q2 += e * e; }
    float var2 = wave_sum(q2) * (1.f / 512.f);
    float rstd2 = rsqrtf(var2 + 1e-5f);
    float g2v[8];
    ld8(g2, (size_t)g2off + c0, f, g2v);
    v8bf o;
#pragma unroll
    for (int j = 0; j < 8; ++j) o[j] = tobf((nx[j] - mean2) * rstd2 * g2v[j]);
    *(v8bf*)(xn + (size_t)row * 512 + c0) = o;
}

// -- x += t ; xn = (stable? stableLN : LN)(x)*g  (one row per WAVE) -----------
__global__ __launch_bounds__(256)
void add_ln_k(const bf16* __restrict__ tin, const void* __restrict__ g, int goff,
              const int* __restrict__ flag, int stable,
              float* __restrict__ x, bf16* __restrict__ xn)
{
    int f = *flag;
    int row = blockIdx.x * 4 + (threadIdx.x >> 6);
    int lane = threadIdx.x & 63;
    int c0 = lane * 8;
    float nx[8];
    {
        v8bf a = *(const v8bf*)(tin + (size_t)row * 512 + c0);
        float* xr = x + (size_t)row * 512 + c0;
        float4 xa = *(float4*)xr, xb = *(float4*)(xr + 4);
        float xv[8] = {xa.x, xa.y, xa.z, xa.w, xb.x, xb.y, xb.z, xb.w};
#pragma unroll
        for (int j = 0; j < 8; ++j) nx[j] = xv[j] + (float)a[j];
        *(float4*)xr       = make_float4(nx[0], nx[1], nx[2], nx[3]);
        *(float4*)(xr + 4) = make_float4(nx[4], nx[5], nx[6], nx[7]);
    }
    float v[8];
#pragma unroll
    for (int j = 0; j < 8; ++j) v[j] = nx[j];
    if (stable) {
        float m = v[0];
#pragma unroll
        for (int j = 1; j < 8; ++j) m = fmaxf(m, v[j]);
        float mx = wave_max(m);
#pragma unroll
        for (int j = 0; j < 8; ++j) v[j] /= mx;
    }
    float s = 0.f;
#pragma unroll
    for (int j = 0; j < 8; ++j) s += v[j];
    float mean = wave_sum(s) * (1.f / 512.f);
    float q = 0.f;
#pragma unroll
    for (int j = 0; j < 8; ++j) { float d = v[j] - mean; q += d * d; }
    float var = wave_sum(q) * (1.f / 512.f);
    float rstd = rsqrtf(var + 1e-5f);
    float gv[8];
    ld8(g, (size_t)goff + c0, f, gv);
    v8bf o;
#pragma unroll
    for (int j = 0; j < 8; ++j) o[j] = tobf((v[j] - mean) * rstd * gv[j]);
    *(v8bf*)(xn + (size_t)row * 512 + c0) = o;
}

// ---------------- merged q + k/v prep (qkv stride 640, rotary via table) -----
// blocks [0,2048): q rows, 16 per block (4/wave, 16 lanes x 4 els each).
// blocks [2048,3200): k/v rows j in [0,1152) x b (4608, 4/block, 1/wave).
// K/Vt are padded to 1152 rows (zeros for j>=1025) so attention's 128-wide
// chunk loads never go out of bounds.
__global__ __launch_bounds__(256)
void qkvprep_k(const bf16* __restrict__ qkv, const void* __restrict__ nkv, int nkoff,
               const int* __restrict__ flag, const float2* __restrict__ rtab,
               bf16* __restrict__ Q, bf16* __restrict__ K, bf16* __restrict__ Vt)
{
    int t = threadIdx.x, lane = t & 63;
    int bid = blockIdx.x;
    if (bid < 2048) {
        int rid = bid * 16 + (t >> 4);            // one row per 16-lane group
        int h = rid & 7;
        int n = (rid >> 3) & 1023;
        int b = rid >> 13;
        int g16 = t & 15;
        int d0 = g16 * 4;
        v4bf a = *(const v4bf*)(qkv + (size_t)((b << 10) | n) * 640 + h * 64 + d0);
        float v[4];
#pragma unroll
        for (int j = 0; j < 4; ++j) v[j] = (float)a[j] * 16.f;
        if (d0 < 32) {                            // rotary, pairs in-lane
            float4 cs = *(const float4*)((const float*)rtab + (size_t)n * 32 + (size_t)(d0 >> 1) * 2);
            float r0 = v[0] * cs.x - v[1] * cs.y;
            float r1 = v[1] * cs.x + v[0] * cs.y;
            float r2 = v[2] * cs.z - v[3] * cs.w;
            float r3 = v[3] * cs.z + v[2] * cs.w;
            v[0] = r0; v[1] = r1; v[2] = r2; v[3] = r3;
        }
        float ss = v[0]*v[0] + v[1]*v[1] + v[2]*v[2] + v[3]*v[3];
#pragma unroll
        for (int o = 1; o < 16; o <<= 1) ss += __shfl_xor(ss, o, 64);
        float sc = 4.f / fmaxf(sqrtf(ss), 1e-12f);
        v4bf ov;
#pragma unroll
        for (int j = 0; j < 4; ++j) ov[j] = tobf(v[j] * sc);
        *(v4bf*)(Q + (((size_t)(b * 8 + h)) * 1024 + n) * 64 + d0) = ov;
    } else {
        int f = *flag;
        int rid = (bid - 2048) * 4 + (t >> 6);
        if (rid >= 4 * 1152) return;
        int j = rid % 1152;
        int b = rid / 1152;
        if (j >= 1025) {
            K[((size_t)b * 1152 + j) * 64 + lane] = f2bf(0.f);
            Vt[((size_t)b * 64 + lane) * 1152 + j] = f2bf(0.f);
            return;
        }
        float kv, vv;
        if (j == 0) {
            kv = ldin(nkv, nkoff + lane, f);
            vv = ldin(nkv, nkoff + 64 + lane, f);
        } else {
            int n = j - 1;
            const bf16* src = qkv + (size_t)(b * 1024 + n) * 640 + 512;
            kv = bf2f(src[lane]);
            vv = bf2f(src[64 + lane]);
            if (lane < 32) {
                float2 cs = rtab[n * 16 + (lane >> 1)];
                float other = __shfl_xor(kv, 1, 64);
                float rot = (lane & 1) ? other : -other;
                kv = kv * cs.x + rot * cs.y;
            }
        }
        float nrm = sqrtf(wave_sum(kv * kv));
        kv = kv / fmaxf(nrm, 1e-12f) * 4.f;
        K[((size_t)b * 1152 + j) * 64 + lane] = f2bf(kv);
        Vt[((size_t)b * 64 + lane) * 1152 + j] = f2bf(vv);
    }
}

// -------- MFMA flash attention, KVBLK=128, NO SPLIT, FIXED-MAX softmax -------
// grid (B*H=32, 16 qtiles), block 256 = 4 waves (16 q-rows each). K/Vt padded
// to 1152 rows so the last chunk's register prefetch stays in-bounds. Bias
// table pre-offset by -16 => p = exp(s + bias'), no online max; l reduced once
// at the end; output normalized in-register and written directly.
__global__ __launch_bounds__(256)
void attn_mfma(const bf16* __restrict__ Q, const bf16* __restrict__ Kg,
               const bf16* __restrict__ Vtg, const float* __restrict__ bias,
               bf16* __restrict__ O)
{
    __shared__ bf16 Ks[128][72];
    __shared__ bf16 Vts[64][136];
    __shared__ bf16 Ps[4][16][136];
    __shared__ float bs[1088];
    const int bh = blockIdx.x, b = bh >> 3, h = bh & 7;
    const int yy = (int)gridDim.y - 1 - (int)blockIdx.y;   // longest first
    const int i0 = yy * 64;
    const int t = threadIdx.x, lane = t & 63, w = t >> 6;
    const int col = lane & 15, quad = lane >> 4, fk = quad * 8;
    const float* bt = bias + h * 1025;
    const bf16* Kb = Kg + (size_t)b * 1152 * 64;
    const bf16* Vb = Vtg + (size_t)b * 64 * 1152;

    // stage bias row into LDS: dist range needed is [0, i0+63]
    for (int idx = t; idx < i0 + 64; idx += 256) bs[idx] = bt[idx];

    v8bf qf[2];
    const bf16* qrow = Q + ((size_t)bh * 1024 + i0 + w * 16 + col) * 64;
    qf[0] = *(const v8bf*)(qrow + fk);
    qf[1] = *(const v8bf*)(qrow + 32 + fk);

    v4f oacc[4];
#pragma unroll
    for (int dt = 0; dt < 4; ++dt) { v4f z = {0.f,0.f,0.f,0.f}; oacc[dt] = z; }
    float lpart[4] = {0.f, 0.f, 0.f, 0.f};

    // chunks of 128 covering j in [0, i0+65]
    const int nch = (i0 + 66 + 127) >> 7;
    const int rK = t >> 3,  cK = (t & 7) * 8;    // K granule coords (+32 rows/rep)
    const int rV = t >> 4,  cV = (t & 15) * 8;   // Vt granule coords (+16 rows/rep)

    v8bf kr[4], vr[4];
#pragma unroll
    for (int r = 0; r < 4; ++r) {
        kr[r] = *(const v8bf*)(Kb + (size_t)(rK + 32 * r) * 64 + cK);
        vr[r] = *(const v8bf*)(Vb + (size_t)(rV + 16 * r) * 1152 + cV);
    }

    for (int ch = 0; ch < nch; ++ch) {
        const int j0 = ch * 128;
        __syncthreads();                                 // prev compute done w/ LDS
#pragma unroll
        for (int r = 0; r < 4; ++r) {
            *(v8bf*)(&Ks[rK + 32 * r][cK])  = kr[r];
            *(v8bf*)(&Vts[rV + 16 * r][cV]) = vr[r];
        }
        if (ch + 1 < nch) {                              // prefetch next chunk
            int j0n = (ch + 1) * 128;
#pragma unroll
            for (int r = 0; r < 4; ++r) {
                kr[r] = *(const v8bf*)(Kb + (size_t)(j0n + rK + 32 * r) * 64 + cK);
                vr[r] = *(const v8bf*)(Vb + (size_t)(rV + 16 * r) * 1152 + j0n + cV);
            }
        }
        __syncthreads();

        // QK^T (8 col-tiles of 16)
        v4f sreg[8];
#pragma unroll
        for (int nt = 0; nt < 8; ++nt) {
            v4f z = {0.f,0.f,0.f,0.f};
            v8bf kf0 = *(const v8bf*)(&Ks[nt * 16 + col][fk]);
            v8bf kf1 = *(const v8bf*)(&Ks[nt * 16 + col][32 + fk]);
            z = __builtin_amdgcn_mfma_f32_16x16x32_bf16(qf[0], kf0, z, 0, 0, 0);
            z = __builtin_amdgcn_mfma_f32_16x16x32_bf16(qf[1], kf1, z, 0, 0, 0);
            sreg[nt] = z;
        }

        // p = exp(s + bias - 16); no max tracking, no cross-lane ops.
        if (j0 + 127 <= i0) {
            // fully-interior chunk: no causal/pad mask, dist >= 0 guaranteed
#pragma unroll
            for (int reg = 0; reg < 4; ++reg) {
                int i = i0 + w * 16 + quad * 4 + reg;
                int dbase = i - j0 - col;
#pragma unroll
                for (int nt = 0; nt < 8; ++nt) {
                    float pp = __expf(sreg[nt][reg] + bs[dbase - nt * 16]);
                    lpart[reg] += pp;
                    Ps[w][quad * 4 + reg][nt * 16 + col] = f2bf(pp);
                }
            }
        } else {
#pragma unroll
            for (int reg = 0; reg < 4; ++reg) {
                int i = i0 + w * 16 + quad * 4 + reg;
#pragma unroll
                for (int nt = 0; nt < 8; ++nt) {
                    int j = j0 + nt * 16 + col;
                    float pp = 0.f;
                    if (j <= i + 1 && j < 1025) {
                        int dist = i - j; if (dist < 0) dist = 0;
                        pp = __expf(sreg[nt][reg] + bs[dist]);
                    }
                    lpart[reg] += pp;
                    Ps[w][quad * 4 + reg][nt * 16 + col] = f2bf(pp);
                }
            }
        }

        // PV: 4 k-slot groups of 32
        v8bf pf[4];
#pragma unroll
        for (int ks = 0; ks < 4; ++ks)
            pf[ks] = *(const v8bf*)(&Ps[w][col][ks * 32 + fk]);
#pragma unroll
        for (int dt = 0; dt < 4; ++dt) {
#pragma unroll
            for (int ks = 0; ks < 4; ++ks) {
                v8bf vf = *(const v8bf*)(&Vts[dt * 16 + col][ks * 32 + fk]);
                oacc[dt] = __builtin_amdgcn_mfma_f32_16x16x32_bf16(pf[ks], vf, oacc[dt], 0, 0, 0);
            }
        }
    }

    // single deferred l reduction (16 cols per row) + normalized direct write
#pragma unroll
    for (int reg = 0; reg < 4; ++reg) {
#pragma unroll
        for (int o = 1; o < 16; o <<= 1) lpart[reg] += __shfl_xor(lpart[reg], o, 64);
        float inv = 1.f / lpart[reg];
        int i = i0 + w * 16 + quad * 4 + reg;
        bf16* orow = O + ((size_t)(b * 1024 + i)) * 512 + h * 64;
#pragma unroll
        for (int dt = 0; dt < 4; ++dt)
            orow[dt * 16 + col] = f2bf(oacc[dt][reg] * inv);
    }
}

// =============================================================================
extern "C" void kernel_launch(void* const* d_in, const int* in_sizes, int n_in,
                              void* d_out, int out_size, void* d_ws, size_t ws_size,
                              hipStream_t stream)
{
    const void* x_in     = d_in[0];
    const void* rpe      = d_in[1];
    const void* g_attn   = d_in[2];
    const void* null_kv  = d_in[3];
    const void* Wq       = d_in[4];
    const void* Wkv      = d_in[5];
    const void* Wo       = d_in[6];
    const void* g_attn_o = d_in[7];
    const void* g_ff     = d_in[8];
    const void* W1       = d_in[9];
    const void* W2       = d_in[10];
    const void* g_final  = d_in[11];
    const void* W_proj   = d_in[12];

    char* wp = (char*)d_ws;
    auto alloc = [&](size_t bytes) {
        char* p = wp; wp += (bytes + 255) & ~(size_t)255; return p;
    };
    float* xf    = (float*)alloc(4096ull * 512 * 4);
    bf16*  xn    = (bf16*) alloc(4096ull * 512 * 2);
    bf16*  tb    = (bf16*) alloc(4096ull * 512 * 2);
    bf16*  ub    = (bf16*) alloc(4096ull * 4096 * 2);
    bf16*  Kb    = (bf16*) alloc(4ull * 1152 * 64 * 2);
    bf16*  Vtb   = (bf16*) alloc(4ull * 64 * 1152 * 2);
    float* btab  = (float*)alloc(8ull * 1025 * 4);
    float2* rtab = (float2*)alloc(16384ull * 8);
    int*   dfl   = (int*)  alloc(256);
    bf16*  WqkvT = (bf16*) alloc(6ull * 640 * 512 * 2);
    bf16*  WoT   = (bf16*) alloc(6ull * 512 * 512 * 2);
    bf16*  W1T   = (bf16*) alloc(6ull * 4096 * 512 * 2);
    bf16*  W2T   = (bf16*) alloc(6ull * 512 * 2048 * 2);
    bf16*  WpT   = (bf16*) alloc(512ull * 512 * 2);
    // aliased into ub (16,777,216 elems; all dead before gemm256_silu writes ub)
    bf16*  qkvb  = ub;                        // 2,621,440 elems
    bf16*  Qb    = ub + 2621440;              // 2,097,152
    bf16*  ob    = ub + 4718592;              // 2,097,152

    detect_k<<<1, 256, 0, stream>>>((const unsigned short*)x_in, dfl);
    prologue_k<<<23265, dim3(32, 8), 0, stream>>>(
        Wq, Wkv, Wo, W1, W2, W_proj, rpe, x_in, g_attn, dfl,
        WqkvT, WoT, W1T, W2T, WpT, btab, rtab, xf, xn);

    for (int l = 0; l < 6; ++l) {
        gemm64<<<dim3(64, 10), 256, 0, stream>>>(xn, WqkvT + (size_t)l * 640 * 512, qkvb, 4096, 640, 512, 512);
        qkvprep_k<<<3200, 256, 0, stream>>>(qkvb, null_kv, l * 128, dfl, rtab, Qb, Kb, Vtb);
        attn_mfma<<<dim3(32, 16), 256, 0, stream>>>(Qb, Kb, Vtb, btab, ob);
        gemm64<<<dim3(64, 8), 256, 0, stream>>>(ob, WoT + (size_t)l * 512 * 512, tb, 4096, 512, 512, 512);
        addln_ln_k<<<1024, 256, 0, stream>>>(tb, g_attn_o, l * 512, g_ff, l * 512, dfl, xf, xn);
        gemm256_silu<<<dim3(16, 16), 512, 0, stream>>>(xn, W1T + (size_t)l * 4096 * 512, ub, 512, 512);
        gemm64<<<dim3(64, 8), 256, 0, stream>>>(ub, W2T + (size_t)l * 512 * 2048, tb, 4096, 512, 2048, 2048);
        if (l < 5)
            add_ln_k<<<1024, 256, 0, stream>>>(tb, g_attn, (l + 1) * 512, dfl, 0, xf, xn);
        else
            add_ln_k<<<1024, 256, 0, stream>>>(tb, g_final, 0, dfl, 1, xf, xn);
    }
    gemm64_out<<<dim3(64, 8), 256, 0, stream>>>(xn, WpT, d_out, 4096, 512, 512, 512, dfl);
}